// Round 3
// baseline (32.458 us; speedup 1.0000x reference)
//
#include <hip/hip_runtime.h>

#define C_DIM 32
#define M_DIM 64
#define NG    8          // NGEN
#define TAB   (M_DIM * NG)
#define NPB   512        // nodes per KA block
#define ST    9          // padded stride for m-indexed LDS tables (bank spread)

// ---------------------------------------------------------------------------
// KA: node-parallel. Each block recomputes the (m,g) tables from B/Pi (cheap:
// ~130 expf/thread, B reads are L2 hits), then writes h_vals/h_idx for its
// NPB nodes with conflict-free LDS gathers + coalesced scalar stores, and
// fills the graph-boundary array starts[0..G]. Block 0 exports the like-table
// to ws for KB. No single-block serial phase anywhere.
// ---------------------------------------------------------------------------
__global__ void __launch_bounds__(256)
cgmm_main(const float* __restrict__ B, const float* __restrict__ Pi,
          const int* __restrict__ x, const int* __restrict__ batch,
          float* __restrict__ out_hv, float* __restrict__ out_hi,
          float* __restrict__ like_tab, int* __restrict__ starts,
          int N, int G) {
    __shared__ float K_s[C_DIM * NG];      // Pi[c,g] - lseB[c,g] - lsePi[g]
    __shared__ float lsePi_s[NG];
    __shared__ float hval_s[M_DIM * ST];   // padded stride 9
    __shared__ float hidx_s[M_DIM * ST];
    __shared__ float like_s[TAB];          // compact (export layout)
    __shared__ int   xs_s[NPB];
    __shared__ int   bs_s[NPB + 1];        // batch[base-1 .. base+NPB-1]

    const int tid  = threadIdx.x;
    const int base = blockIdx.x * NPB;

    // coalesced staging of x and batch
    for (int i = tid; i < NPB; i += 256) {
        const int n = base + i;
        if (n < N) xs_s[i] = x[n];
    }
    for (int i = tid; i <= NPB; i += 256) {
        const int n = base + i - 1;
        bs_s[i] = (n >= 0 && n < N) ? batch[n] : 0;
    }

    // lsePi[g]
    if (tid < NG) {
        float mx = -1e30f;
        #pragma unroll
        for (int c = 0; c < C_DIM; ++c) mx = fmaxf(mx, Pi[c * NG + tid]);
        float s = 0.f;
        #pragma unroll
        for (int c = 0; c < C_DIM; ++c) s += expf(Pi[c * NG + tid] - mx);
        lsePi_s[tid] = logf(s) + mx;
    }
    __syncthreads();

    // K[c,g] = Pi - lseB - lsePi   (thread <-> (c,g))
    {
        const int g = tid & 7;
        const float* bp = B + (tid >> 3) * (M_DIM * NG) + g;
        float mx = -1e30f;
        #pragma unroll
        for (int m = 0; m < M_DIM; ++m) mx = fmaxf(mx, bp[m * NG]);
        float s = 0.f;
        #pragma unroll
        for (int m = 0; m < M_DIM; ++m) s += expf(bp[m * NG] - mx);
        K_s[tid] = Pi[tid] - (logf(s) + mx) - lsePi_s[g];
    }
    __syncthreads();

    // table entries: thread (q=tid>>3, g) handles m = q and q+32
    {
        const int q = tid >> 3, g = tid & 7;
        #pragma unroll
        for (int h = 0; h < 2; ++h) {
            const int m = q + 32 * h;
            float L[C_DIM];
            float best = -1e30f; int bidx = 0;
            #pragma unroll
            for (int c = 0; c < C_DIM; ++c) {
                float v = B[c * (M_DIM * NG) + m * NG + g] + K_s[c * NG + g];
                L[c] = v;
                if (v > best) { best = v; bidx = c; }   // strict >, first max
            }
            float se = 0.f, la = 0.f;
            #pragma unroll
            for (int c = 0; c < C_DIM; ++c) {
                float e = expf(L[c] - best);
                se += e; la += e * L[c];
            }
            hval_s[m * ST + g] = 1.f / se;
            hidx_s[m * ST + g] = (float)bidx;
            like_s[m * NG + g] = la / se;
        }
    }
    __syncthreads();

    // export like-table once for KB
    if (blockIdx.x == 0) {
        for (int i = tid; i < TAB; i += 256) like_tab[i] = like_s[i];
    }

    // graph-boundary fill (total work across all threads = G)
    for (int i = tid; i < NPB; i += 256) {
        const int n = base + i;
        if (n >= N) break;
        const int bn = bs_s[i + 1];
        if (n == 0) {
            for (int j = 0; j <= bn; ++j) starts[j] = 0;
        } else {
            const int bp2 = bs_s[i];
            for (int j = bp2 + 1; j <= bn; ++j) starts[j] = n;
        }
        if (n == N - 1) {
            for (int j = bn + 1; j <= G; ++j) starts[j] = N;
        }
    }

    // node writes: thread (s = tid>>3, g = tid&7); wave stores 256B contiguous
    {
        const int s = tid >> 3, g = tid & 7;
        #pragma unroll
        for (int k = 0; k < NPB / 32; ++k) {
            const int i = k * 32 + s;
            const int n = base + i;
            if (n >= N) break;
            const int xm = xs_s[i];
            out_hv[(size_t)n * NG + g] = hval_s[xm * ST + g];
            out_hi[(size_t)n * NG + g] = hidx_s[xm * ST + g];
        }
    }
}

// ---------------------------------------------------------------------------
// KB: one 64-lane wave per graph (4 per block). Direct starts[] lookup,
// padded like-table in LDS, deterministic shuffle-reduced segment sum.
// ---------------------------------------------------------------------------
__global__ void __launch_bounds__(256)
cgmm_like(const int* __restrict__ x, const int* __restrict__ starts,
          const float* __restrict__ like_tab, float* __restrict__ out, int G) {
    __shared__ float like_s[M_DIM * ST];
    const int tid = threadIdx.x;
    for (int i = tid; i < TAB; i += 256)
        like_s[(i >> 3) * ST + (i & 7)] = like_tab[i];
    __syncthreads();

    const int j = blockIdx.x * 4 + (tid >> 6);
    if (j >= G) return;
    const int start = starts[j];
    const int end   = starts[j + 1];

    const int slot = (tid >> 3) & 7;
    const int g    = tid & 7;

    float acc = 0.f;
    for (int n = start + slot; n < end; n += 8)
        acc += like_s[x[n] * ST + g];

    acc += __shfl_xor(acc, 8);
    acc += __shfl_xor(acc, 16);
    acc += __shfl_xor(acc, 32);
    if ((tid & 63) < NG) out[(size_t)j * NG + g] = acc;
}

extern "C" void kernel_launch(void* const* d_in, const int* in_sizes, int n_in,
                              void* d_out, int out_size, void* d_ws, size_t ws_size,
                              hipStream_t stream) {
    const float* B     = (const float*)d_in[0];   // (C, M, NG)
    const float* Pi    = (const float*)d_in[1];   // (C, NG)
    const int*   x     = (const int*)d_in[2];     // (N,)
    const int*   batch = (const int*)d_in[3];     // (N,) sorted
    const int N = in_sizes[2];
    const int G = (out_size - 2 * N * NG) / NG;   // out = [G*NG | N*NG | N*NG]

    float* like_tab = (float*)d_ws;                      // 512 floats
    int*   starts   = (int*)((char*)d_ws + 4096);        // G+1 ints

    float* out_like = (float*)d_out;
    float* out_hv   = out_like + (size_t)G * NG;
    float* out_hi   = out_hv + (size_t)N * NG;

    cgmm_main<<<(N + NPB - 1) / NPB, 256, 0, stream>>>(B, Pi, x, batch,
                                                       out_hv, out_hi,
                                                       like_tab, starts, N, G);
    cgmm_like<<<(G + 3) / 4, 256, 0, stream>>>(x, starts, like_tab, out_like, G);
}

// Round 4
// 21.778 us; speedup vs baseline: 1.4904x; 1.4904x over previous
//
#include <hip/hip_runtime.h>

#define C_DIM 32
#define M_DIM 64
#define NG    8          // NGEN
#define TAB   (M_DIM * NG)
#define ST    9          // padded stride for m-indexed LDS tables (bank spread)
#define SPB   1024       // nodes per starts-scan block (KA)
#define NPB   512        // nodes per node-write block (KB)

// ---------------------------------------------------------------------------
// KA: fused prep. Blocks [0, nsb): scan batch, fill starts[0..G] (boundary
// detection, total work = G). Block nsb: compute the 3x512 (m,g) tables into
// ws (like, hval, hidx). These two jobs are independent -> one dispatch.
// ---------------------------------------------------------------------------
__global__ void __launch_bounds__(256)
cgmm_prep(const float* __restrict__ B, const float* __restrict__ Pi,
          const int* __restrict__ batch,
          float* __restrict__ tab, int* __restrict__ starts,
          int N, int G, int nsb) {
    const int tid = threadIdx.x;

    if ((int)blockIdx.x < nsb) {
        // ---- starts-fill blocks ----
        const int base = blockIdx.x * SPB;
        for (int i = tid; i < SPB; i += 256) {
            const int n = base + i;
            if (n >= N) break;
            const int bn = batch[n];
            if (n == 0) {
                for (int j = 0; j <= bn; ++j) starts[j] = 0;
            } else {
                const int bp = batch[n - 1];
                for (int j = bp + 1; j <= bn; ++j) starts[j] = n;  // empty if equal
            }
            if (n == N - 1) {
                for (int j = bn + 1; j <= G; ++j) starts[j] = N;
            }
        }
        return;
    }

    // ---- tables block (one block) ----
    __shared__ float Pis[C_DIM * NG];
    __shared__ float lsePi_s[NG];
    __shared__ float K_s[C_DIM * NG];   // Pi - lseB - lsePi

    Pis[tid] = Pi[tid];                 // 256 threads == 256 entries
    __syncthreads();

    if (tid < NG) {
        float mx = -1e30f;
        #pragma unroll
        for (int c = 0; c < C_DIM; ++c) mx = fmaxf(mx, Pis[c * NG + tid]);
        float s = 0.f;
        #pragma unroll
        for (int c = 0; c < C_DIM; ++c) s += expf(Pis[c * NG + tid] - mx);
        lsePi_s[tid] = logf(s) + mx;
    }
    __syncthreads();

    {   // thread <-> (c,g): lseB over m, then K
        const int g = tid & 7;
        const float* bp = B + (tid >> 3) * (M_DIM * NG) + g;
        float mx = -1e30f;
        #pragma unroll
        for (int m = 0; m < M_DIM; ++m) mx = fmaxf(mx, bp[m * NG]);
        float s = 0.f;
        #pragma unroll
        for (int m = 0; m < M_DIM; ++m) s += expf(bp[m * NG] - mx);
        K_s[tid] = Pis[tid] - (logf(s) + mx) - lsePi_s[g];
    }
    __syncthreads();

    {   // thread (q,g) handles m = q and q+32
        const int q = tid >> 3, g = tid & 7;
        #pragma unroll
        for (int h = 0; h < 2; ++h) {
            const int m = q + 32 * h;
            float L[C_DIM];
            float best = -1e30f; int bidx = 0;
            #pragma unroll
            for (int c = 0; c < C_DIM; ++c) {
                float v = B[c * (M_DIM * NG) + m * NG + g] + K_s[c * NG + g];
                L[c] = v;
                if (v > best) { best = v; bidx = c; }   // strict >, first max
            }
            float se = 0.f, la = 0.f;
            #pragma unroll
            for (int c = 0; c < C_DIM; ++c) {
                float e = expf(L[c] - best);
                se += e; la += e * L[c];
            }
            const int idx = m * NG + g;
            tab[idx]           = la / se;     // like
            tab[TAB + idx]     = 1.f / se;    // hval = max posterior
            tab[2 * TAB + idx] = (float)bidx; // hidx
        }
    }
}

// ---------------------------------------------------------------------------
// KB: fused output. Blocks [0, nnb): node-parallel hv/hi writes (padded LDS
// gather, coalesced 256B/wave scalar stores). Blocks [nnb, ...): one 64-lane
// wave per graph, deterministic shuffle-reduced likelihood via starts[].
// Both jobs depend only on KA's outputs -> run concurrently in one dispatch.
// ---------------------------------------------------------------------------
__global__ void __launch_bounds__(256)
cgmm_write(const int* __restrict__ x, const int* __restrict__ starts,
           const float* __restrict__ tab,
           float* __restrict__ out_like, float* __restrict__ out_hv,
           float* __restrict__ out_hi, int N, int G, int nnb) {
    const int tid = threadIdx.x;

    if ((int)blockIdx.x < nnb) {
        // ---- node-write blocks ----
        __shared__ float hval_s[M_DIM * ST];
        __shared__ float hidx_s[M_DIM * ST];
        __shared__ int   xs_s[NPB];
        const int base = blockIdx.x * NPB;

        for (int i = tid; i < TAB; i += 256) {
            const int m = i >> 3, g = i & 7;
            hval_s[m * ST + g] = tab[TAB + i];
            hidx_s[m * ST + g] = tab[2 * TAB + i];
        }
        for (int i = tid; i < NPB; i += 256) {
            const int n = base + i;
            if (n < N) xs_s[i] = x[n];
        }
        __syncthreads();

        const int s = tid >> 3, g = tid & 7;
        #pragma unroll
        for (int k = 0; k < NPB / 32; ++k) {
            const int i = k * 32 + s;
            const int n = base + i;
            if (n >= N) break;
            const int xm = xs_s[i];
            out_hv[(size_t)n * NG + g] = hval_s[xm * ST + g];
            out_hi[(size_t)n * NG + g] = hidx_s[xm * ST + g];
        }
        return;
    }

    // ---- like blocks: 4 graphs per block, one wave each ----
    __shared__ float like_s[M_DIM * ST];
    for (int i = tid; i < TAB; i += 256)
        like_s[(i >> 3) * ST + (i & 7)] = tab[i];
    __syncthreads();

    const int j = ((int)blockIdx.x - nnb) * 4 + (tid >> 6);
    if (j >= G) return;
    const int start = starts[j];
    const int end   = starts[j + 1];

    const int slot = (tid >> 3) & 7;
    const int g    = tid & 7;

    float acc = 0.f;
    for (int n = start + slot; n < end; n += 8)
        acc += like_s[x[n] * ST + g];

    acc += __shfl_xor(acc, 8);
    acc += __shfl_xor(acc, 16);
    acc += __shfl_xor(acc, 32);
    if ((tid & 63) < NG) out_like[(size_t)j * NG + g] = acc;
}

extern "C" void kernel_launch(void* const* d_in, const int* in_sizes, int n_in,
                              void* d_out, int out_size, void* d_ws, size_t ws_size,
                              hipStream_t stream) {
    const float* B     = (const float*)d_in[0];   // (C, M, NG)
    const float* Pi    = (const float*)d_in[1];   // (C, NG)
    const int*   x     = (const int*)d_in[2];     // (N,)
    const int*   batch = (const int*)d_in[3];     // (N,) sorted
    const int N = in_sizes[2];
    const int G = (out_size - 2 * N * NG) / NG;   // out = [G*NG | N*NG | N*NG]

    float* tab    = (float*)d_ws;                      // 1536 floats
    int*   starts = (int*)((char*)d_ws + 8192);        // G+1 ints

    float* out_like = (float*)d_out;
    float* out_hv   = out_like + (size_t)G * NG;
    float* out_hi   = out_hv + (size_t)N * NG;

    const int nsb = (N + SPB - 1) / SPB;               // starts-scan blocks
    const int nnb = (N + NPB - 1) / NPB;               // node-write blocks
    const int nlb = (G + 3) / 4;                       // like blocks

    cgmm_prep<<<nsb + 1, 256, 0, stream>>>(B, Pi, batch, tab, starts, N, G, nsb);
    cgmm_write<<<nnb + nlb, 256, 0, stream>>>(x, starts, tab, out_like,
                                              out_hv, out_hi, N, G, nnb);
}

// Round 5
// 19.981 us; speedup vs baseline: 1.6244x; 1.0899x over previous
//
#include <hip/hip_runtime.h>

#define C_DIM 32
#define M_DIM 64
#define NG    8            // NGEN
#define TAB   (M_DIM * NG) // 512
#define ST    9            // padded stride for m-indexed LDS tables
#define BST   520          // padded c-stride (floats) for staged B (520%32==8 -> conflict-free both phases)
#define SPB   2048         // nodes per starts-scan block (512 threads)

// ---------------------------------------------------------------------------
// D1: blocks [0,nsb) scan batch -> starts[0..G]. Block nsb computes the
// 3x512 (m,g) tables entirely from LDS-staged B (coalesced float4 staging,
// padded stride => conflict-free in both the (c,g)-lane and (m,g)-lane phases).
// ---------------------------------------------------------------------------
__global__ void __launch_bounds__(512)
cgmm_prep(const float* __restrict__ B, const float* __restrict__ Pi,
          const int* __restrict__ batch,
          float* __restrict__ tab, int* __restrict__ starts,
          int N, int G, int nsb) {
    const int tid = threadIdx.x;

    if ((int)blockIdx.x < nsb) {
        // ---- starts-fill blocks ----
        const int base = blockIdx.x * SPB;
        for (int i = tid; i < SPB; i += 512) {
            const int n = base + i;
            if (n >= N) break;
            const int bn = batch[n];
            if (n == 0) {
                for (int j = 0; j <= bn; ++j) starts[j] = 0;
            } else {
                const int bp = batch[n - 1];
                for (int j = bp + 1; j <= bn; ++j) starts[j] = n;  // empty if equal
            }
            if (n == N - 1) {
                for (int j = bn + 1; j <= G; ++j) starts[j] = N;
            }
        }
        return;
    }

    // ---- tables block ----
    __shared__ float Bs[C_DIM * BST];     // 66,560 B, padded c-stride
    __shared__ float Pis[C_DIM * NG];
    __shared__ float lsePi_s[NG];
    __shared__ float K_s[C_DIM * NG];     // Pi - lseB - lsePi

    // coalesced float4 staging of B into padded layout (128 float4 per c row)
    {
        const float4* B4 = (const float4*)B;
        float4* Bs4 = (float4*)Bs;
        #pragma unroll
        for (int i = tid; i < (C_DIM * M_DIM * NG) / 4; i += 512) {
            Bs4[(i >> 7) * (BST / 4) + (i & 127)] = B4[i];
        }
        if (tid < C_DIM * NG / 4) ((float4*)Pis)[tid] = ((const float4*)Pi)[tid];
    }
    __syncthreads();

    if (tid < NG) {
        float mx = -1e30f;
        #pragma unroll
        for (int c = 0; c < C_DIM; ++c) mx = fmaxf(mx, Pis[c * NG + tid]);
        float s = 0.f;
        #pragma unroll
        for (int c = 0; c < C_DIM; ++c) s += expf(Pis[c * NG + tid] - mx);
        lsePi_s[tid] = logf(s) + mx;
    }
    __syncthreads();

    if (tid < C_DIM * NG) {   // lanes=(c,g): Bs bank = (8c+g)%32 = lane%32, conflict-free
        const int c = tid >> 3, g = tid & 7;
        const float* bp = Bs + c * BST + g;
        float mx = -1e30f;
        #pragma unroll
        for (int m = 0; m < M_DIM; ++m) mx = fmaxf(mx, bp[m * NG]);
        float s = 0.f;
        #pragma unroll
        for (int m = 0; m < M_DIM; ++m) s += expf(bp[m * NG] - mx);
        K_s[tid] = Pis[tid] - (logf(s) + mx) - lsePi_s[g];
    }
    __syncthreads();

    {   // 512 threads = (m,g) pairs; Bs bank = lane%32, K_s broadcast
        const int m = tid >> 3, g = tid & 7;
        float L[C_DIM];
        float best = -1e30f; int bidx = 0;
        #pragma unroll
        for (int c = 0; c < C_DIM; ++c) {
            float v = Bs[c * BST + m * NG + g] + K_s[c * NG + g];
            L[c] = v;
            if (v > best) { best = v; bidx = c; }   // strict >, first max
        }
        float se = 0.f, la = 0.f;
        #pragma unroll
        for (int c = 0; c < C_DIM; ++c) {
            float e = expf(L[c] - best);
            se += e; la += e * L[c];
        }
        tab[tid]           = la / se;     // like
        tab[TAB + tid]     = 1.f / se;    // hval = max posterior
        tab[2 * TAB + tid] = (float)bidx; // hidx
    }
}

// ---------------------------------------------------------------------------
// D2: one 64-lane wave per graph (4 per block). Single pass over the graph's
// nodes: LDS table gathers (padded, ~2 lanes/bank), coalesced 256B/wave
// hv/hi stores, deterministic shuffle-reduced likelihood.
// ---------------------------------------------------------------------------
__global__ void __launch_bounds__(256)
cgmm_write(const int* __restrict__ x, const int* __restrict__ starts,
           const float* __restrict__ tab,
           float* __restrict__ out_like, float* __restrict__ out_hv,
           float* __restrict__ out_hi, int G) {
    __shared__ float like_s[M_DIM * ST];
    __shared__ float hval_s[M_DIM * ST];
    __shared__ float hidx_s[M_DIM * ST];
    const int tid = threadIdx.x;
    for (int i = tid; i < TAB; i += 256) {
        const int p = (i >> 3) * ST + (i & 7);
        like_s[p] = tab[i];
        hval_s[p] = tab[TAB + i];
        hidx_s[p] = tab[2 * TAB + i];
    }
    __syncthreads();

    const int j = blockIdx.x * 4 + (tid >> 6);
    if (j >= G) return;
    const int start = starts[j];
    const int end   = starts[j + 1];

    const int slot = (tid >> 3) & 7;
    const int g    = tid & 7;

    float acc = 0.f;
    for (int n = start + slot; n < end; n += 8) {
        const int xm = x[n];                 // 8 lanes/addr broadcast
        const int p  = xm * ST + g;
        acc += like_s[p];
        out_hv[(size_t)n * NG + g] = hval_s[p];   // wave: 256B contiguous
        out_hi[(size_t)n * NG + g] = hidx_s[p];
    }
    acc += __shfl_xor(acc, 8);
    acc += __shfl_xor(acc, 16);
    acc += __shfl_xor(acc, 32);
    if ((tid & 63) < NG) out_like[(size_t)j * NG + g] = acc;
}

extern "C" void kernel_launch(void* const* d_in, const int* in_sizes, int n_in,
                              void* d_out, int out_size, void* d_ws, size_t ws_size,
                              hipStream_t stream) {
    const float* B     = (const float*)d_in[0];   // (C, M, NG)
    const float* Pi    = (const float*)d_in[1];   // (C, NG)
    const int*   x     = (const int*)d_in[2];     // (N,)
    const int*   batch = (const int*)d_in[3];     // (N,) sorted
    const int N = in_sizes[2];
    const int G = (out_size - 2 * N * NG) / NG;   // out = [G*NG | N*NG | N*NG]

    float* tab    = (float*)d_ws;                 // 1536 floats
    int*   starts = (int*)((char*)d_ws + 8192);   // G+1 ints

    float* out_like = (float*)d_out;
    float* out_hv   = out_like + (size_t)G * NG;
    float* out_hi   = out_hv + (size_t)N * NG;

    const int nsb = (N + SPB - 1) / SPB;          // starts-scan blocks

    cgmm_prep<<<nsb + 1, 512, 0, stream>>>(B, Pi, batch, tab, starts, N, G, nsb);
    cgmm_write<<<(G + 3) / 4, 256, 0, stream>>>(x, starts, tab, out_like,
                                                out_hv, out_hi, G);
}